// Round 6
// baseline (42.930 us; speedup 1.0000x reference)
//
#include <hip/hip_runtime.h>
#include <cmath>

#define NK       10000
#define GROUP    2000
#define SEQ_L    256
#define FEAT_DIM 20000
#define NBATCH   16

typedef _Float16 half8 __attribute__((ext_vector_type(8)));
typedef float    f32x4 __attribute__((ext_vector_type(4)));

// ---------------------------------------------------------------------------
// Kernel A: dilated conv features via MFMA (fp16 3-term split = ~f32 accuracy).
//   Per block: 128 kernels (Mtile) x 256 positions of one (dilation, batch).
//   B = im2col(x) staged hi/lo in LDS as [kb][t][8] (conflict-free b128 frags);
//   A (weights) + bias loaded global->reg per lane. 2 waves x 64 rows each.
//   y[n][t] = sum_k' W[n][k'] X[k'][t];  max/PPV folded per 16-col chunk.
// grid = (16 Mtiles, 5 groups, 16 batches), block = 128.
// ---------------------------------------------------------------------------
__launch_bounds__(128)
__global__ void rocket_mfma(const float* __restrict__ x_enc,  // (16,256,3)
                            const float* __restrict__ Wk,     // (10000,3,9)
                            const float* __restrict__ bias,   // (10000,)
                            float* __restrict__ feat)         // (16,20000)
{
    __shared__ __align__(16) float     xp[3 * 384];   // padded x: [c][t+64]
    __shared__ __align__(16) _Float16  Bh[4 * 256 * 8];  // [kb][t][j]
    __shared__ __align__(16) _Float16  Bl[4 * 256 * 8];

    const int mt  = blockIdx.x;        // M tile 0..15
    const int gi  = blockIdx.y;        // dilation group 0..4
    const int b   = blockIdx.z;
    const int d   = 1 << gi;
    const int tid = threadIdx.x;
    const int l   = tid & 63;
    const int wv  = tid >> 6;          // wave 0..1 -> row half
    const int kb  = l >> 4;            // k-block 0..3 (A/B frag k-offset 8*kb)
    const int lr  = l & 15;

    // ---- stage padded x (zero, sync, fill) ----
    for (int i = tid; i < 3 * 384; i += 128) xp[i] = 0.f;
    __syncthreads();
    for (int e = tid; e < SEQ_L * 3; e += 128) {
        const int t = e / 3;
        const int c = e - t * 3;
        xp[c * 384 + 64 + t] = x_enc[(b * SEQ_L + t) * 3 + c];
    }

    // ---- A fragments + bias: global -> registers (no LDS) ----
    // A[row][k]: lane holds row = base+tt*16+lr, k = kb*8+j  (j=0..7)
    float awf[4][8];
#pragma unroll
    for (int tt = 0; tt < 4; ++tt) {
        const int nl = mt * 128 + wv * 64 + tt * 16 + lr;
        const int n  = gi * GROUP + (nl < GROUP ? nl : GROUP - 1);
#pragma unroll
        for (int j = 0; j < 8; ++j) {
            const int k = kb * 8 + j;
            awf[tt][j] = (k < 27) ? Wk[n * 27 + k] : 0.f;
        }
    }
    half8 ahi[4], alo[4];
#pragma unroll
    for (int tt = 0; tt < 4; ++tt)
#pragma unroll
        for (int j = 0; j < 8; ++j) {
            const _Float16 h = (_Float16)awf[tt][j];
            ahi[tt][j] = h;
            alo[tt][j] = (_Float16)(awf[tt][j] - (float)h);
        }
    // bias per output row: row = 4*kb + r within tile tt
    float bsv[4][4];
#pragma unroll
    for (int tt = 0; tt < 4; ++tt)
#pragma unroll
        for (int r = 0; r < 4; ++r) {
            const int nl = mt * 128 + wv * 64 + tt * 16 + kb * 4 + r;
            bsv[tt][r] = bias[gi * GROUP + (nl < GROUP ? nl : GROUP - 1)];
        }

    __syncthreads();   // xp ready

    // ---- build im2col B hi/lo in LDS: B[k'][t] stored as [k'>>3][t][k'&7] ----
    // thread (kg = tid>>5, tl = tid&31) writes t = tl + 32*i  (coalesced b128)
    {
        const int kg = tid >> 5;       // 0..3
        const int tl = tid & 31;
#pragma unroll
        for (int i = 0; i < 8; ++i) {
            const int t = tl + 32 * i;
            half8 hv, lv;
#pragma unroll
            for (int kk = 0; kk < 8; ++kk) {
                const int k2 = kg * 8 + kk;
                float v = 0.f;
                if (k2 < 27) {
                    const int c  = (k2 >= 18) ? 2 : (k2 >= 9 ? 1 : 0);
                    const int k9 = k2 - c * 9;
                    v = xp[c * 384 + 64 + t + (k9 - 4) * d];
                }
                const _Float16 h = (_Float16)v;
                hv[kk] = h;
                lv[kk] = (_Float16)(v - (float)h);
            }
            *(half8*)&Bh[(kg * 256 + t) * 8] = hv;
            *(half8*)&Bl[(kg * 256 + t) * 8] = lv;
        }
    }
    __syncthreads();

    // ---- MFMA main loop: 16 N-chunks of 16 cols ----
    float mx[4][4], cnt[4][4];
#pragma unroll
    for (int tt = 0; tt < 4; ++tt)
#pragma unroll
        for (int r = 0; r < 4; ++r) { mx[tt][r] = -INFINITY; cnt[tt][r] = 0.f; }

#pragma unroll
    for (int ch = 0; ch < 16; ++ch) {
        const int t = ch * 16 + lr;    // this lane's column
        const half8 bh = *(const half8*)&Bh[(kb * 256 + t) * 8];
        const half8 bl = *(const half8*)&Bl[(kb * 256 + t) * 8];
#pragma unroll
        for (int tt = 0; tt < 4; ++tt) {
            f32x4 acc = {0.f, 0.f, 0.f, 0.f};
            acc = __builtin_amdgcn_mfma_f32_16x16x32_f16(ahi[tt], bh, acc, 0, 0, 0);
            acc = __builtin_amdgcn_mfma_f32_16x16x32_f16(alo[tt], bh, acc, 0, 0, 0);
            acc = __builtin_amdgcn_mfma_f32_16x16x32_f16(ahi[tt], bl, acc, 0, 0, 0);
#pragma unroll
            for (int r = 0; r < 4; ++r) {
                const float y = acc[r] + bsv[tt][r];
                mx[tt][r]  = fmaxf(mx[tt][r], y);
                cnt[tt][r] += (y > 0.f) ? 1.f : 0.f;
            }
        }
    }

    // ---- reduce over the 16 cols (lanes sharing same row group) ----
#pragma unroll
    for (int tt = 0; tt < 4; ++tt)
#pragma unroll
        for (int r = 0; r < 4; ++r) {
#pragma unroll
            for (int m = 1; m < 16; m <<= 1) {
                mx[tt][r]  = fmaxf(mx[tt][r], __shfl_xor(mx[tt][r], m));
                cnt[tt][r] += __shfl_xor(cnt[tt][r], m);
            }
        }

    if (lr == 0) {
        float* fb = feat + b * FEAT_DIM + gi * 4000;
#pragma unroll
        for (int tt = 0; tt < 4; ++tt)
#pragma unroll
            for (int r = 0; r < 4; ++r) {
                const int nl = mt * 128 + wv * 64 + tt * 16 + kb * 4 + r;
                if (nl < GROUP) {
                    fb[nl]         = mx[tt][r];
                    fb[2000 + nl]  = cnt[tt][r] * (1.0f / 256.0f);
                }
            }
    }
}

// ---------------------------------------------------------------------------
// Kernel B: fused BN-stats + GEMV partial. grid = 32 slices of 625 features.
//   phase 1: g,h for the slice (into LDS); phase 2: 16-thread group per batch
//   accumulates 10 class sums; shfl-reduce; write partial[slice][b][10].
// ---------------------------------------------------------------------------
__launch_bounds__(256)
__global__ void bn_gemv(const float* __restrict__ feat,
                        const float* __restrict__ gamma,
                        const float* __restrict__ beta,
                        const float* __restrict__ linW,   // (20000,10)
                        float* __restrict__ partial)      // (32,16,10)
{
    __shared__ float gs[625], hs[625];
    const int sl  = blockIdx.x;
    const int f0  = sl * 625;
    const int tid = threadIdx.x;

    for (int i = tid; i < 625; i += 256) {
        const int f = f0 + i;
        float s = 0.f, ss = 0.f;
#pragma unroll
        for (int b = 0; b < NBATCH; ++b) {
            const float v = feat[b * FEAT_DIM + f];
            s += v; ss += v * v;
        }
        const float mu  = s * (1.f / NBATCH);
        const float var = ss * (1.f / NBATCH) - mu * mu;
        const float gg  = gamma[f] * rsqrtf(var + 1e-5f);
        gs[i] = gg;
        hs[i] = beta[f] - mu * gg;
    }
    __syncthreads();

    const int bb = tid >> 4;        // batch 0..15
    const int ft = tid & 15;
    float acc[10];
#pragma unroll
    for (int c = 0; c < 10; ++c) acc[c] = 0.f;

    for (int i = ft; i < 625; i += 16) {
        const int f = f0 + i;
        const float tv = fmaf(feat[bb * FEAT_DIM + f], gs[i], hs[i]);
#pragma unroll
        for (int c = 0; c < 10; ++c) acc[c] = fmaf(tv, linW[f * 10 + c], acc[c]);
    }
#pragma unroll
    for (int c = 0; c < 10; ++c)
#pragma unroll
        for (int m = 1; m < 16; m <<= 1) acc[c] += __shfl_xor(acc[c], m);

    if (ft == 0) {
#pragma unroll
        for (int c = 0; c < 10; ++c)
            partial[(sl * NBATCH + bb) * 10 + c] = acc[c];
    }
}

// ---------------------------------------------------------------------------
// Kernel C: final reduce over 32 slices + bias. 1 block, 160 threads.
// ---------------------------------------------------------------------------
__launch_bounds__(160)
__global__ void gemv_final(const float* __restrict__ partial,
                           const float* __restrict__ linB,
                           float* __restrict__ out)
{
    const int tid = threadIdx.x;       // 0..159 = b*10 + c
    const int c   = tid % 10;
    float s = linB[c];
#pragma unroll
    for (int sl = 0; sl < 32; ++sl) s += partial[sl * 160 + tid];
    out[tid] = s;
}

// ---------------------------------------------------------------------------
extern "C" void kernel_launch(void* const* d_in, const int* in_sizes, int n_in,
                              void* d_out, int out_size, void* d_ws, size_t ws_size,
                              hipStream_t stream) {
    const float* x     = (const float*)d_in[0];
    const float* Wk    = (const float*)d_in[1];
    const float* bias  = (const float*)d_in[2];
    const float* gamma = (const float*)d_in[3];
    const float* beta  = (const float*)d_in[4];
    const float* linW  = (const float*)d_in[5];
    const float* linB  = (const float*)d_in[6];
    float* out = (float*)d_out;

    float* feat    = (float*)d_ws;                 // 16*20000
    float* partial = feat + NBATCH * FEAT_DIM;     // 32*160

    rocket_mfma<<<dim3(16, 5, NBATCH), 128, 0, stream>>>(x, Wk, bias, feat);
    bn_gemv<<<dim3(32), 256, 0, stream>>>(feat, gamma, beta, linW, partial);
    gemv_final<<<dim3(1), 160, 0, stream>>>(partial, linB, out);
}

// Round 7
// 36.279 us; speedup vs baseline: 1.1833x; 1.1833x over previous
//
#include <hip/hip_runtime.h>
#include <cmath>

#define NK       10000
#define GROUP    2000
#define SEQ_L    256
#define FEAT_DIM 20000
#define NBATCH   16

typedef _Float16 half8 __attribute__((ext_vector_type(8)));
typedef float    f32x4 __attribute__((ext_vector_type(4)));

// ---------------------------------------------------------------------------
// Kernel 1: build im2col B (hi/lo fp16 split) ONCE per (group, batch).
//   B[k'][t] for k' = c*9+k9 (27, padded to 32), stored as [kb][t][j]
//   (kb = k'>>3, j = k'&7) so a GEMM lane's fragment is 16 contiguous bytes.
// grid = (5, 16), block = 256.
// ---------------------------------------------------------------------------
__launch_bounds__(256)
__global__ void build_B(const float* __restrict__ x_enc,   // (16,256,3)
                        _Float16* __restrict__ Bh_g,
                        _Float16* __restrict__ Bl_g)
{
    __shared__ __align__(16) float xp[3 * 384];   // [c][t+64], zero-padded
    const int gi  = blockIdx.x;
    const int b   = blockIdx.y;
    const int d   = 1 << gi;
    const int tid = threadIdx.x;

    for (int i = tid; i < 3 * 384; i += 256) xp[i] = 0.f;
    __syncthreads();
    for (int e = tid; e < SEQ_L * 3; e += 256) {
        const int t = e / 3;
        const int c = e - t * 3;
        xp[c * 384 + 64 + t] = x_enc[(b * SEQ_L + t) * 3 + c];
    }
    __syncthreads();

    const int base = (gi * NBATCH + b) * 1024;    // 4 kb * 256 t
#pragma unroll
    for (int q = 0; q < 4; ++q) {
        const int idx = q * 256 + tid;            // kb*256 + t
        const int kb  = idx >> 8;
        const int t   = idx & 255;
        half8 hv, lv;
#pragma unroll
        for (int kk = 0; kk < 8; ++kk) {
            const int k2 = kb * 8 + kk;
            float v = 0.f;
            if (k2 < 27) {
                const int c  = (k2 >= 18) ? 2 : (k2 >= 9 ? 1 : 0);
                const int k9 = k2 - c * 9;
                v = xp[c * 384 + 64 + t + (k9 - 4) * d];
            }
            const _Float16 h = (_Float16)v;
            hv[kk] = h;
            lv[kk] = (_Float16)(v - (float)h);
        }
        *(half8*)&Bh_g[(base + idx) * 8] = hv;
        *(half8*)&Bl_g[(base + idx) * 8] = lv;
    }
}

// ---------------------------------------------------------------------------
// Kernel 2: MFMA GEMM + max/PPV epilogue. No LDS. 128 thr = 2 waves; each
//   wave owns 64 rows (4 tiles of 16). B fragments are coalesced 16B global
//   loads from the prebuilt buffer. 3-term fp16 split = ~f32 accuracy.
// grid = (16 Mtiles, 5 groups, 16 batches).
// ---------------------------------------------------------------------------
__launch_bounds__(128)
__global__ void gemm_feat(const _Float16* __restrict__ Bh_g,
                          const _Float16* __restrict__ Bl_g,
                          const float* __restrict__ Wk,     // (10000,3,9)
                          const float* __restrict__ bias,   // (10000,)
                          float* __restrict__ feat)         // (16,20000)
{
    const int mt  = blockIdx.x;
    const int gi  = blockIdx.y;
    const int b   = blockIdx.z;
    const int tid = threadIdx.x;
    const int l   = tid & 63;
    const int wv  = tid >> 6;
    const int kb  = l >> 4;            // k-block 0..3
    const int lr  = l & 15;

    // A fragments: lane holds row = mt*128 + wv*64 + tt*16 + lr, k = kb*8+j
    half8 ahi[4], alo[4];
#pragma unroll
    for (int tt = 0; tt < 4; ++tt) {
        const int nl = mt * 128 + wv * 64 + tt * 16 + lr;
        const int n  = gi * GROUP + (nl < GROUP ? nl : GROUP - 1);
#pragma unroll
        for (int j = 0; j < 8; ++j) {
            const int k = kb * 8 + j;
            const float w = (k < 27) ? Wk[n * 27 + k] : 0.f;
            const _Float16 h = (_Float16)w;
            ahi[tt][j] = h;
            alo[tt][j] = (_Float16)(w - (float)h);
        }
    }
    float bsv[4][4];
#pragma unroll
    for (int tt = 0; tt < 4; ++tt)
#pragma unroll
        for (int r = 0; r < 4; ++r) {
            const int nl = mt * 128 + wv * 64 + tt * 16 + kb * 4 + r;
            bsv[tt][r] = bias[gi * GROUP + (nl < GROUP ? nl : GROUP - 1)];
        }

    const _Float16* bhp = Bh_g + ((gi * NBATCH + b) * 1024 + kb * 256) * 8;
    const _Float16* blp = Bl_g + ((gi * NBATCH + b) * 1024 + kb * 256) * 8;

    float mx[4][4], cnt[4][4];
#pragma unroll
    for (int tt = 0; tt < 4; ++tt)
#pragma unroll
        for (int r = 0; r < 4; ++r) { mx[tt][r] = -INFINITY; cnt[tt][r] = 0.f; }

#pragma unroll
    for (int ch = 0; ch < 16; ++ch) {
        const int t = ch * 16 + lr;
        const half8 bh = *(const half8*)&bhp[t * 8];
        const half8 bl = *(const half8*)&blp[t * 8];
#pragma unroll
        for (int tt = 0; tt < 4; ++tt) {
            f32x4 acc = {0.f, 0.f, 0.f, 0.f};
            acc = __builtin_amdgcn_mfma_f32_16x16x32_f16(ahi[tt], bh, acc, 0, 0, 0);
            acc = __builtin_amdgcn_mfma_f32_16x16x32_f16(alo[tt], bh, acc, 0, 0, 0);
            acc = __builtin_amdgcn_mfma_f32_16x16x32_f16(ahi[tt], bl, acc, 0, 0, 0);
#pragma unroll
            for (int r = 0; r < 4; ++r) {
                const float y = acc[r] + bsv[tt][r];
                mx[tt][r]  = fmaxf(mx[tt][r], y);
                cnt[tt][r] += (y > 0.f) ? 1.f : 0.f;
            }
        }
    }

    // reduce over the 16 columns (lanes with same row group)
#pragma unroll
    for (int tt = 0; tt < 4; ++tt)
#pragma unroll
        for (int r = 0; r < 4; ++r) {
#pragma unroll
            for (int m = 1; m < 16; m <<= 1) {
                mx[tt][r]  = fmaxf(mx[tt][r], __shfl_xor(mx[tt][r], m));
                cnt[tt][r] += __shfl_xor(cnt[tt][r], m);
            }
        }

    if (lr == 0) {
        float* fb = feat + b * FEAT_DIM + gi * 4000;
#pragma unroll
        for (int tt = 0; tt < 4; ++tt)
#pragma unroll
            for (int r = 0; r < 4; ++r) {
                const int nl = mt * 128 + wv * 64 + tt * 16 + kb * 4 + r;
                if (nl < GROUP) {
                    fb[nl]        = mx[tt][r];
                    fb[2000 + nl] = cnt[tt][r] * (1.0f / 256.0f);
                }
            }
    }
}

// ---------------------------------------------------------------------------
// Kernel 3: fused BN-stats + GEMV partial. grid = 80 slices of 250 features.
// ---------------------------------------------------------------------------
__launch_bounds__(256)
__global__ void bn_gemv(const float* __restrict__ feat,
                        const float* __restrict__ gamma,
                        const float* __restrict__ beta,
                        const float* __restrict__ linW,   // (20000,10)
                        float* __restrict__ partial)      // (80,16,10)
{
    __shared__ float gs[250], hs[250];
    const int sl  = blockIdx.x;
    const int f0  = sl * 250;
    const int tid = threadIdx.x;

    if (tid < 250) {
        const int f = f0 + tid;
        float s = 0.f, ss = 0.f;
#pragma unroll
        for (int b = 0; b < NBATCH; ++b) {
            const float v = feat[b * FEAT_DIM + f];
            s += v; ss += v * v;
        }
        const float mu  = s * (1.f / NBATCH);
        const float var = ss * (1.f / NBATCH) - mu * mu;
        const float gg  = gamma[f] * rsqrtf(var + 1e-5f);
        gs[tid] = gg;
        hs[tid] = beta[f] - mu * gg;
    }
    __syncthreads();

    const int bb = tid >> 4;        // batch 0..15
    const int ft = tid & 15;
    float acc[10];
#pragma unroll
    for (int c = 0; c < 10; ++c) acc[c] = 0.f;

    for (int i = ft; i < 250; i += 16) {
        const int f = f0 + i;
        const float tv = fmaf(feat[bb * FEAT_DIM + f], gs[i], hs[i]);
#pragma unroll
        for (int c = 0; c < 10; ++c) acc[c] = fmaf(tv, linW[f * 10 + c], acc[c]);
    }
#pragma unroll
    for (int c = 0; c < 10; ++c)
#pragma unroll
        for (int m = 1; m < 16; m <<= 1) acc[c] += __shfl_xor(acc[c], m);

    if (ft == 0) {
#pragma unroll
        for (int c = 0; c < 10; ++c)
            partial[(sl * NBATCH + bb) * 10 + c] = acc[c];
    }
}

// ---------------------------------------------------------------------------
// Kernel 4: final reduce over 80 slices + bias. 1 block, 160 threads.
// ---------------------------------------------------------------------------
__launch_bounds__(160)
__global__ void gemv_final(const float* __restrict__ partial,
                           const float* __restrict__ linB,
                           float* __restrict__ out)
{
    const int tid = threadIdx.x;       // 0..159 = b*10 + c
    const int c   = tid % 10;
    float s = linB[c];
#pragma unroll
    for (int sl = 0; sl < 80; ++sl) s += partial[sl * 160 + tid];
    out[tid] = s;
}

// ---------------------------------------------------------------------------
extern "C" void kernel_launch(void* const* d_in, const int* in_sizes, int n_in,
                              void* d_out, int out_size, void* d_ws, size_t ws_size,
                              hipStream_t stream) {
    const float* x     = (const float*)d_in[0];
    const float* Wk    = (const float*)d_in[1];
    const float* bias  = (const float*)d_in[2];
    const float* gamma = (const float*)d_in[3];
    const float* beta  = (const float*)d_in[4];
    const float* linW  = (const float*)d_in[5];
    const float* linB  = (const float*)d_in[6];
    float* out = (float*)d_out;

    float*    feat    = (float*)d_ws;                       // 320000 f
    float*    partial = feat + NBATCH * FEAT_DIM;           // 12800 f
    _Float16* Bh      = (_Float16*)(partial + 80 * 160);    // 655360 h
    _Float16* Bl      = Bh + 5 * NBATCH * 1024 * 8;         // 655360 h

    build_B<<<dim3(5, NBATCH), 256, 0, stream>>>(x, Bh, Bl);
    gemm_feat<<<dim3(16, 5, NBATCH), 128, 0, stream>>>(Bh, Bl, Wk, bias, feat);
    bn_gemv<<<dim3(80), 256, 0, stream>>>(feat, gamma, beta, linW, partial);
    gemv_final<<<dim3(1), 160, 0, stream>>>(partial, linB, out);
}